// Round 8
// baseline (180.594 us; speedup 1.0000x reference)
//
#include <hip/hip_runtime.h>

// PPISP R8. R3/R5/R7 all flat at ~59-62us with every pipe <25% busy despite
// varying occupancy/block-shape/prefetch. Invariant across them: 4px/thread
// => 48B lane stride => every rgb/out b128 instruction spans 48 cache lines;
// ~380 L1 line-requests per thread-iter. Hypothesis: TA/L1 address-path
// serialization caps the stream at ~1.9TB/s (R4's "3TB/s" was cheap linear
// scratch on top of the same slow stream; R1's worse pattern gave 1.33).
// R8: 2px/thread (24B stride; rgb/out as 3xfloat2, pc as lane-contiguous
// float4, idx as int2) halves max span; 2048 blocks x 256thr = 8 blocks/CU
// (LDS 18.9KB: m21->bf16); precompute split to separate kernel (staging is a
// pure b128 copy); sigmoid-form CRF (12 trans/px instead of 15):
// out = rcp(1+exp2(b*log2(t)-a*log2(xc))) + d.

__device__ __forceinline__ unsigned bf16r(float x) {
    unsigned b = __float_as_uint(x);
    return (b + 0x7fffu + ((b >> 16) & 1u)) >> 16;
}
__device__ __forceinline__ unsigned packbf(float lo, float hi) {
    return bf16r(lo) | (bf16r(hi) << 16);
}
__device__ __forceinline__ float ulo(unsigned u) { return __uint_as_float(u << 16); }
__device__ __forceinline__ float uhi(unsigned u) { return __uint_as_float(u & 0xffff0000u); }
__device__ __forceinline__ float ush(unsigned short s) { return __uint_as_float(((unsigned)s) << 16); }

// d_ws layout: [0,16000) uint4 frame table A (bf16 pairs);
//              [16000,16896) float cam table (8 cams x 28 floats);
//              [16896,18896) ushort frame table B (m21 bf16).
__global__ void ppisp_pre(const float* __restrict__ expo,
                          const float* __restrict__ colorp,
                          const float* __restrict__ vigp,
                          const float* __restrict__ crfp,
                          uint4* __restrict__ wsA,
                          float* __restrict__ wsCam,
                          unsigned short* __restrict__ wsB,
                          int num_frames, int ncam) {
    int tid = blockIdx.x * blockDim.x + threadIdx.x;
    if (tid < num_frames) {
        float e = exp2f(expo[tid]);
        const float* cp = colorp + tid * 8;
        float g_r = e * expf(cp[0]);
        float g_b = e * expf(cp[1]);
        uint4 A;
        A.x = packbf(g_r, e);      // g_r, g_g
        A.y = packbf(g_b, cp[2]);  // g_b, m01
        A.z = packbf(cp[3], cp[4]);// m02, m10
        A.w = packbf(cp[5], cp[6]);// m12, m20
        wsA[tid] = A;
        wsB[tid] = (unsigned short)bf16r(cp[7]);  // m21
    }
    if (tid < ncam * 3) {
        int c = tid / 3, ch = tid % 3;
        const float* vp = vigp + tid * 5;
        const float* cf = crfp + tid * 4;
        float* r = wsCam + c * 28 + ch * 9;
        r[0] = vp[0]; r[1] = vp[1]; r[2] = vp[2]; r[3] = vp[3]; r[4] = vp[4];
        r[5] = log1pf(expf(cf[0])) + 0.3f;
        r[6] = log1pf(expf(cf[1])) + 0.3f;
        r[7] = log1pf(expf(cf[2])) + 0.1f;
        r[8] = cf[3];
        if (ch == 0) wsCam[c * 28 + 27] = 0.f;
    }
}

__device__ __forceinline__ void px_compute(
    float rr, float gg, float bb, float pxx, float pyy, int camI, int frmI,
    float invW, float invH,
    const uint4* __restrict__ sA, const unsigned short* __restrict__ sB,
    const float4* __restrict__ scam4,
    float& o0, float& o1, float& o2)
{
    uint4 A = sA[frmI];
    float m21 = ush(sB[frmI]);
    float g_r = ulo(A.x), g_g = uhi(A.x);
    float g_b = ulo(A.y), m01 = uhi(A.y);
    float m02 = ulo(A.z), m10 = uhi(A.z);
    float m12 = ulo(A.w), m20 = uhi(A.w);

    int cb = camI * 7;
    float4 q0 = scam4[cb + 0];
    float4 q1 = scam4[cb + 1];
    float4 q2 = scam4[cb + 2];
    float4 q3 = scam4[cb + 3];
    float4 q4 = scam4[cb + 4];
    float4 q5 = scam4[cb + 5];
    float4 q6 = scam4[cb + 6];

    float u = pxx * invW - 0.5f;
    float v = pyy * invH - 0.5f;

    float cx0 = q0.x, cy0 = q0.y, a10 = q0.z, a20 = q0.w, a30 = q1.x;
    float aa0 = q1.y, bb0 = q1.z, cc0 = q1.w, dd0 = q2.x;
    float cx1 = q2.y, cy1 = q2.z, a11 = q2.w, a21 = q3.x, a31 = q3.y;
    float aa1 = q3.z, bb1 = q3.w, cc1 = q4.x, dd1 = q4.y;
    float cx2 = q4.z, cy2 = q4.w, a12 = q5.x, a22 = q5.y, a32 = q5.z;
    float aa2 = q5.w, bb2 = q6.x, cc2 = q6.y, dd2 = q6.z;

    float du0 = u - cx0, dv0 = v - cy0;
    float du1 = u - cx1, dv1 = v - cy1;
    float du2 = u - cx2, dv2 = v - cy2;
    float r20 = du0 * du0 + dv0 * dv0;
    float r21 = du1 * du1 + dv1 * dv1;
    float r22 = du2 * du2 + dv2 * dv2;
    float fa0 = 1.0f + r20 * (a10 + r20 * (a20 + r20 * a30));
    float fa1 = 1.0f + r21 * (a11 + r21 * (a21 + r21 * a31));
    float fa2 = 1.0f + r22 * (a12 + r22 * (a22 + r22 * a32));

    float x0 = rr * g_r * fa0;
    float x1 = gg * g_g * fa1;
    float x2 = bb * g_b * fa2;

    float y0 = x0 + m01 * x1 + m02 * x2;
    float y1 = m10 * x0 + x1 + m12 * x2;
    float y2 = m20 * x0 + m21 * x1 + x2;

    float xc0 = fminf(fmaxf(y0, 1e-6f), 1.0f);
    float xc1 = fminf(fmaxf(y1, 1e-6f), 1.0f);
    float xc2 = fminf(fmaxf(y2, 1e-6f), 1.0f);

    // out = xa/(xa+tb)+d = rcp(1 + exp2(b*log2(t) - a*log2(xc))) + d
    float lx0 = __builtin_amdgcn_logf(xc0);
    float lx1 = __builtin_amdgcn_logf(xc1);
    float lx2 = __builtin_amdgcn_logf(xc2);
    float t0 = cc0 * (1.0f - xc0) + 1e-6f;
    float t1 = cc1 * (1.0f - xc1) + 1e-6f;
    float t2 = cc2 * (1.0f - xc2) + 1e-6f;
    float lt0 = __builtin_amdgcn_logf(t0);
    float lt1 = __builtin_amdgcn_logf(t1);
    float lt2 = __builtin_amdgcn_logf(t2);
    float z0 = bb0 * lt0 - aa0 * lx0;
    float z1 = bb1 * lt1 - aa1 * lx1;
    float z2 = bb2 * lt2 - aa2 * lx2;
    o0 = __builtin_amdgcn_rcpf(1.0f + __builtin_amdgcn_exp2f(z0)) + dd0;
    o1 = __builtin_amdgcn_rcpf(1.0f + __builtin_amdgcn_exp2f(z1)) + dd1;
    o2 = __builtin_amdgcn_rcpf(1.0f + __builtin_amdgcn_exp2f(z2)) + dd2;
}

__global__ __launch_bounds__(256, 4) void ppisp_main(
    const uint4*  __restrict__ wsA,
    const float4* __restrict__ wsCam4,
    const unsigned* __restrict__ wsBu,
    const float2* __restrict__ rgb2,
    const float4* __restrict__ pc4,
    const int2*   __restrict__ cam2,
    const int2*   __restrict__ frm2,
    const int*    __restrict__ resw,
    const int*    __restrict__ resh,
    float2* __restrict__ out2,
    int ngroups, int groups_per_block, int num_frames, int ncam)
{
    __shared__ uint4 sA[1000];      // 16,000 B
    __shared__ float4 scam4s[56];   //    896 B
    __shared__ unsigned sBu[500];   //  2,000 B  (m21 bf16)

    int tid = threadIdx.x;
    for (int i = tid; i < 1000; i += 256) sA[i] = wsA[i];
    if (tid < 56) scam4s[tid] = wsCam4[tid];
    for (int i = tid; i < 500; i += 256) sBu[i] = wsBu[i];
    __syncthreads();

    const unsigned short* sB = (const unsigned short*)sBu;
    float invW = 1.0f / (float)resw[0];
    float invH = 1.0f / (float)resh[0];

    int gbase = blockIdx.x * groups_per_block;
    int gend = gbase + groups_per_block;
    if (gend > ngroups) gend = ngroups;

    int g = gbase + tid;
    if (g >= gend) return;

    // prologue: iteration-0 loads (2 pixels: 24B rgb as 3xfloat2, pc float4,
    // idx int2 each)
    float2 a0 = rgb2[(size_t)g * 3 + 0];
    float2 a1 = rgb2[(size_t)g * 3 + 1];
    float2 a2 = rgb2[(size_t)g * 3 + 2];
    float4 P  = pc4[g];
    int2 cams = cam2[g];
    int2 frms = frm2[g];

    while (true) {
        int gn = g + 256;
        bool more = gn < gend;
        float2 na0, na1, na2;
        float4 nP;
        int2 ncams, nfrms;
        if (more) {
            na0 = rgb2[(size_t)gn * 3 + 0];
            na1 = rgb2[(size_t)gn * 3 + 1];
            na2 = rgb2[(size_t)gn * 3 + 2];
            nP  = pc4[gn];
            ncams = cam2[gn];
            nfrms = frm2[gn];
        }

        // pixel 0: rgb = (a0.x, a0.y, a1.x), pc = (P.x, P.y)
        // pixel 1: rgb = (a1.y, a2.x, a2.y), pc = (P.z, P.w)
        float o00, o01, o02, o10, o11, o12;
        px_compute(a0.x, a0.y, a1.x, P.x, P.y, cams.x, frms.x,
                   invW, invH, sA, sB, scam4s, o00, o01, o02);
        px_compute(a1.y, a2.x, a2.y, P.z, P.w, cams.y, frms.y,
                   invW, invH, sA, sB, scam4s, o10, o11, o12);

        out2[(size_t)g * 3 + 0] = make_float2(o00, o01);
        out2[(size_t)g * 3 + 1] = make_float2(o02, o10);
        out2[(size_t)g * 3 + 2] = make_float2(o11, o12);

        if (!more) break;
        g = gn;
        a0 = na0; a1 = na1; a2 = na2;
        P = nP; cams = ncams; frms = nfrms;
    }
}

extern "C" void kernel_launch(void* const* d_in, const int* in_sizes, int n_in,
                              void* d_out, int out_size, void* d_ws, size_t ws_size,
                              hipStream_t stream) {
    const float* expo   = (const float*)d_in[0];  // [NUM_FRAMES]
    const float* vigp   = (const float*)d_in[1];  // [NUM_CAMERAS,3,5]
    const float* colorp = (const float*)d_in[2];  // [NUM_FRAMES,8]
    const float* crfp   = (const float*)d_in[3];  // [NUM_CAMERAS,3,4]
    const float* rgb    = (const float*)d_in[4];  // [N,3]
    const float* pc     = (const float*)d_in[5];  // [N,2]
    const int*   cam    = (const int*)d_in[6];    // [N]
    const int*   frm    = (const int*)d_in[7];    // [N]
    const int*   rw     = (const int*)d_in[8];    // scalar
    const int*   rh     = (const int*)d_in[9];    // scalar

    int num_frames = in_sizes[0];   // 1000
    int ncam = in_sizes[1] / 15;    // 8
    int N = in_sizes[4] / 3;        // 4,194,304

    uint4* wsA = (uint4*)d_ws;
    float* wsCam = (float*)((char*)d_ws + 16000);
    unsigned short* wsB = (unsigned short*)((char*)d_ws + 16896);

    int pre_threads = 256;
    int pre_blocks = (num_frames + pre_threads - 1) / pre_threads;
    if (pre_blocks < 1) pre_blocks = 1;
    ppisp_pre<<<pre_blocks, pre_threads, 0, stream>>>(
        expo, colorp, vigp, crfp, wsA, wsCam, wsB, num_frames, ncam);

    int ngroups = N / 2;            // 2,097,152 two-pixel groups
    int blocks = 2048;              // 8 blocks/CU x 256 CU
    int groups_per_block = (ngroups + blocks - 1) / blocks;  // 1024 -> 4 iters/thread
    ppisp_main<<<blocks, 256, 0, stream>>>(
        wsA, (const float4*)wsCam, (const unsigned*)wsB,
        (const float2*)rgb, (const float4*)pc, (const int2*)cam, (const int2*)frm,
        rw, rh, (float2*)d_out,
        ngroups, groups_per_block, num_frames, ncam);
}

// Round 9
// 179.954 us; speedup vs baseline: 1.0036x; 1.0036x over previous
//
#include <hip/hip_runtime.h>

// PPISP R9. R3/R5/R7/R8 invariants: ~58us, VALU ~20%, occupancy pinned ~35%
// (~3 waves/SIMD), app-bandwidth ~2.9TB/s (FETCH 57MB < 117MB ideal: L3
// serves half the reads). Nothing saturated => waves stall ~75% of the time.
// Hypothesis A: 1-deep prefetch over 2-4 iterations never forms a pipeline;
// per-iter stall (~1K cyc global+LDS+FP chain) multiplies into wall time.
// R9: exactly 8 iterations/thread with a hand-unrolled 4-deep prefetch ring
// (named slots L0..L3 -> all register-resident, no runtime indexing). Loads
// for iter i+4 issue after compute of iter i: ~3 step-times of lead >> 900cy
// HBM latency, ~14KB in flight per wave. 1024 blocks x 256thr = 4 blocks/CU.
// Everything else identical to R8 (tables, sigmoid CRF, float2 2px scheme).

__device__ __forceinline__ unsigned bf16r(float x) {
    unsigned b = __float_as_uint(x);
    return (b + 0x7fffu + ((b >> 16) & 1u)) >> 16;
}
__device__ __forceinline__ unsigned packbf(float lo, float hi) {
    return bf16r(lo) | (bf16r(hi) << 16);
}
__device__ __forceinline__ float ulo(unsigned u) { return __uint_as_float(u << 16); }
__device__ __forceinline__ float uhi(unsigned u) { return __uint_as_float(u & 0xffff0000u); }
__device__ __forceinline__ float ush(unsigned short s) { return __uint_as_float(((unsigned)s) << 16); }

// d_ws layout: [0,16000) uint4 frame table A (bf16 pairs);
//              [16000,16896) float cam table (8 cams x 28 floats);
//              [16896,18896) ushort frame table B (m21 bf16).
__global__ void ppisp_pre(const float* __restrict__ expo,
                          const float* __restrict__ colorp,
                          const float* __restrict__ vigp,
                          const float* __restrict__ crfp,
                          uint4* __restrict__ wsA,
                          float* __restrict__ wsCam,
                          unsigned short* __restrict__ wsB,
                          int num_frames, int ncam) {
    int tid = blockIdx.x * blockDim.x + threadIdx.x;
    if (tid < num_frames) {
        float e = exp2f(expo[tid]);
        const float* cp = colorp + tid * 8;
        float g_r = e * expf(cp[0]);
        float g_b = e * expf(cp[1]);
        uint4 A;
        A.x = packbf(g_r, e);
        A.y = packbf(g_b, cp[2]);
        A.z = packbf(cp[3], cp[4]);
        A.w = packbf(cp[5], cp[6]);
        wsA[tid] = A;
        wsB[tid] = (unsigned short)bf16r(cp[7]);
    }
    if (tid < ncam * 3) {
        int c = tid / 3, ch = tid % 3;
        const float* vp = vigp + tid * 5;
        const float* cf = crfp + tid * 4;
        float* r = wsCam + c * 28 + ch * 9;
        r[0] = vp[0]; r[1] = vp[1]; r[2] = vp[2]; r[3] = vp[3]; r[4] = vp[4];
        r[5] = log1pf(expf(cf[0])) + 0.3f;
        r[6] = log1pf(expf(cf[1])) + 0.3f;
        r[7] = log1pf(expf(cf[2])) + 0.1f;
        r[8] = cf[3];
        if (ch == 0) wsCam[c * 28 + 27] = 0.f;
    }
}

struct GIn {
    float2 a0, a1, a2;  // 2 pixels' rgb (6 floats)
    float4 P;           // 2 pixels' coords
    int2 c, f;          // cam/frame idcs
};

__device__ __forceinline__ GIn loadg(const float2* __restrict__ rgb2,
                                     const float4* __restrict__ pc4,
                                     const int2* __restrict__ cam2,
                                     const int2* __restrict__ frm2,
                                     int g) {
    GIn x;
    x.a0 = rgb2[(size_t)g * 3 + 0];
    x.a1 = rgb2[(size_t)g * 3 + 1];
    x.a2 = rgb2[(size_t)g * 3 + 2];
    x.P  = pc4[g];
    x.c  = cam2[g];
    x.f  = frm2[g];
    return x;
}

__device__ __forceinline__ void px_compute(
    float rr, float gg, float bb, float pxx, float pyy, int camI, int frmI,
    float invW, float invH,
    const uint4* __restrict__ sA, const unsigned short* __restrict__ sB,
    const float4* __restrict__ scam4,
    float& o0, float& o1, float& o2)
{
    uint4 A = sA[frmI];
    float m21 = ush(sB[frmI]);
    float g_r = ulo(A.x), g_g = uhi(A.x);
    float g_b = ulo(A.y), m01 = uhi(A.y);
    float m02 = ulo(A.z), m10 = uhi(A.z);
    float m12 = ulo(A.w), m20 = uhi(A.w);

    int cb = camI * 7;
    float4 q0 = scam4[cb + 0];
    float4 q1 = scam4[cb + 1];
    float4 q2 = scam4[cb + 2];
    float4 q3 = scam4[cb + 3];
    float4 q4 = scam4[cb + 4];
    float4 q5 = scam4[cb + 5];
    float4 q6 = scam4[cb + 6];

    float u = pxx * invW - 0.5f;
    float v = pyy * invH - 0.5f;

    float cx0 = q0.x, cy0 = q0.y, a10 = q0.z, a20 = q0.w, a30 = q1.x;
    float aa0 = q1.y, bb0 = q1.z, cc0 = q1.w, dd0 = q2.x;
    float cx1 = q2.y, cy1 = q2.z, a11 = q2.w, a21 = q3.x, a31 = q3.y;
    float aa1 = q3.z, bb1 = q3.w, cc1 = q4.x, dd1 = q4.y;
    float cx2 = q4.z, cy2 = q4.w, a12 = q5.x, a22 = q5.y, a32 = q5.z;
    float aa2 = q5.w, bb2 = q6.x, cc2 = q6.y, dd2 = q6.z;

    float du0 = u - cx0, dv0 = v - cy0;
    float du1 = u - cx1, dv1 = v - cy1;
    float du2 = u - cx2, dv2 = v - cy2;
    float r20 = du0 * du0 + dv0 * dv0;
    float r21 = du1 * du1 + dv1 * dv1;
    float r22 = du2 * du2 + dv2 * dv2;
    float fa0 = 1.0f + r20 * (a10 + r20 * (a20 + r20 * a30));
    float fa1 = 1.0f + r21 * (a11 + r21 * (a21 + r21 * a31));
    float fa2 = 1.0f + r22 * (a12 + r22 * (a22 + r22 * a32));

    float x0 = rr * g_r * fa0;
    float x1 = gg * g_g * fa1;
    float x2 = bb * g_b * fa2;

    float y0 = x0 + m01 * x1 + m02 * x2;
    float y1 = m10 * x0 + x1 + m12 * x2;
    float y2 = m20 * x0 + m21 * x1 + x2;

    float xc0 = fminf(fmaxf(y0, 1e-6f), 1.0f);
    float xc1 = fminf(fmaxf(y1, 1e-6f), 1.0f);
    float xc2 = fminf(fmaxf(y2, 1e-6f), 1.0f);

    float lx0 = __builtin_amdgcn_logf(xc0);
    float lx1 = __builtin_amdgcn_logf(xc1);
    float lx2 = __builtin_amdgcn_logf(xc2);
    float t0 = cc0 * (1.0f - xc0) + 1e-6f;
    float t1 = cc1 * (1.0f - xc1) + 1e-6f;
    float t2 = cc2 * (1.0f - xc2) + 1e-6f;
    float lt0 = __builtin_amdgcn_logf(t0);
    float lt1 = __builtin_amdgcn_logf(t1);
    float lt2 = __builtin_amdgcn_logf(t2);
    float z0 = bb0 * lt0 - aa0 * lx0;
    float z1 = bb1 * lt1 - aa1 * lx1;
    float z2 = bb2 * lt2 - aa2 * lx2;
    o0 = __builtin_amdgcn_rcpf(1.0f + __builtin_amdgcn_exp2f(z0)) + dd0;
    o1 = __builtin_amdgcn_rcpf(1.0f + __builtin_amdgcn_exp2f(z1)) + dd1;
    o2 = __builtin_amdgcn_rcpf(1.0f + __builtin_amdgcn_exp2f(z2)) + dd2;
}

__device__ __forceinline__ void computeg(
    const GIn& L, int g,
    float invW, float invH,
    const uint4* __restrict__ sA, const unsigned short* __restrict__ sB,
    const float4* __restrict__ scam4,
    float2* __restrict__ out2)
{
    float o00, o01, o02, o10, o11, o12;
    px_compute(L.a0.x, L.a0.y, L.a1.x, L.P.x, L.P.y, L.c.x, L.f.x,
               invW, invH, sA, sB, scam4, o00, o01, o02);
    px_compute(L.a1.y, L.a2.x, L.a2.y, L.P.z, L.P.w, L.c.y, L.f.y,
               invW, invH, sA, sB, scam4, o10, o11, o12);
    out2[(size_t)g * 3 + 0] = make_float2(o00, o01);
    out2[(size_t)g * 3 + 1] = make_float2(o02, o10);
    out2[(size_t)g * 3 + 2] = make_float2(o11, o12);
}

__global__ __launch_bounds__(256, 4) void ppisp_main(
    const uint4*  __restrict__ wsA,
    const float4* __restrict__ wsCam4,
    const unsigned* __restrict__ wsBu,
    const float2* __restrict__ rgb2,
    const float4* __restrict__ pc4,
    const int2*   __restrict__ cam2,
    const int2*   __restrict__ frm2,
    const int*    __restrict__ resw,
    const int*    __restrict__ resh,
    float2* __restrict__ out2,
    int ngroups, int groups_per_block, int num_frames, int ncam)
{
    __shared__ uint4 sA[1000];      // 16,000 B
    __shared__ float4 scam4s[56];   //    896 B
    __shared__ unsigned sBu[500];   //  2,000 B

    int tid = threadIdx.x;
    for (int i = tid; i < 1000; i += 256) sA[i] = wsA[i];
    if (tid < 56) scam4s[tid] = wsCam4[tid];
    for (int i = tid; i < 500; i += 256) sBu[i] = wsBu[i];
    __syncthreads();

    const unsigned short* sB = (const unsigned short*)sBu;
    float invW = 1.0f / (float)resw[0];
    float invH = 1.0f / (float)resh[0];

    // exactly 8 iterations per thread, stride 256 within the block's chunk
    int t0 = blockIdx.x * groups_per_block + tid;

    // ---- prologue: fill 4-deep ring ----
    GIn L0 = loadg(rgb2, pc4, cam2, frm2, t0);
    GIn L1 = loadg(rgb2, pc4, cam2, frm2, t0 + 256);
    GIn L2 = loadg(rgb2, pc4, cam2, frm2, t0 + 512);
    GIn L3 = loadg(rgb2, pc4, cam2, frm2, t0 + 768);

    // ---- steady state: compute slot, refill slot 4 iterations ahead ----
    computeg(L0, t0,        invW, invH, sA, sB, scam4s, out2);
    L0 = loadg(rgb2, pc4, cam2, frm2, t0 + 1024);
    computeg(L1, t0 + 256,  invW, invH, sA, sB, scam4s, out2);
    L1 = loadg(rgb2, pc4, cam2, frm2, t0 + 1280);
    computeg(L2, t0 + 512,  invW, invH, sA, sB, scam4s, out2);
    L2 = loadg(rgb2, pc4, cam2, frm2, t0 + 1536);
    computeg(L3, t0 + 768,  invW, invH, sA, sB, scam4s, out2);
    L3 = loadg(rgb2, pc4, cam2, frm2, t0 + 1792);

    // ---- drain ----
    computeg(L0, t0 + 1024, invW, invH, sA, sB, scam4s, out2);
    computeg(L1, t0 + 1280, invW, invH, sA, sB, scam4s, out2);
    computeg(L2, t0 + 1536, invW, invH, sA, sB, scam4s, out2);
    computeg(L3, t0 + 1792, invW, invH, sA, sB, scam4s, out2);
}

extern "C" void kernel_launch(void* const* d_in, const int* in_sizes, int n_in,
                              void* d_out, int out_size, void* d_ws, size_t ws_size,
                              hipStream_t stream) {
    const float* expo   = (const float*)d_in[0];  // [NUM_FRAMES]
    const float* vigp   = (const float*)d_in[1];  // [NUM_CAMERAS,3,5]
    const float* colorp = (const float*)d_in[2];  // [NUM_FRAMES,8]
    const float* crfp   = (const float*)d_in[3];  // [NUM_CAMERAS,3,4]
    const float* rgb    = (const float*)d_in[4];  // [N,3]
    const float* pc     = (const float*)d_in[5];  // [N,2]
    const int*   cam    = (const int*)d_in[6];    // [N]
    const int*   frm    = (const int*)d_in[7];    // [N]
    const int*   rw     = (const int*)d_in[8];    // scalar
    const int*   rh     = (const int*)d_in[9];    // scalar

    int num_frames = in_sizes[0];   // 1000
    int ncam = in_sizes[1] / 15;    // 8
    int N = in_sizes[4] / 3;        // 4,194,304

    uint4* wsA = (uint4*)d_ws;
    float* wsCam = (float*)((char*)d_ws + 16000);
    unsigned short* wsB = (unsigned short*)((char*)d_ws + 16896);

    int pre_threads = 256;
    int pre_blocks = (num_frames + pre_threads - 1) / pre_threads;
    if (pre_blocks < 1) pre_blocks = 1;
    ppisp_pre<<<pre_blocks, pre_threads, 0, stream>>>(
        expo, colorp, vigp, crfp, wsA, wsCam, wsB, num_frames, ncam);

    int ngroups = N / 2;                      // 2,097,152 two-pixel groups
    int blocks = ngroups / (256 * 8);         // 1024 blocks: 8 iters/thread exact
    int groups_per_block = ngroups / blocks;  // 2048
    ppisp_main<<<blocks, 256, 0, stream>>>(
        wsA, (const float4*)wsCam, (const unsigned*)wsB,
        (const float2*)rgb, (const float4*)pc, (const int2*)cam, (const int2*)frm,
        rw, rh, (float2*)d_out,
        ngroups, groups_per_block, num_frames, ncam);
}